// Round 2
// baseline (193.959 us; speedup 1.0000x reference)
//
#include <hip/hip_runtime.h>
#include <hip/hip_bf16.h>
#include <stdint.h>

// out = x @ (W_shared + W_expert)^T + bias   (MoE collapses: positional routing,
// shared expert weights, normalized top-2 gate weights sum to 1)
static constexpr int Mdim = 16384;  // T = B*N tokens
static constexpr int Ndim = 1024;
static constexpr int Kdim = 1024;
// 8-phase 256^2 template: BM=BN=256, BK=64, 512 thr / 8 waves (2M x 4N)
static constexpr int KTILES = Kdim / 64;  // 16

typedef __attribute__((ext_vector_type(8))) __bf16 bf16x8;
typedef __attribute__((ext_vector_type(4))) float f32x4;
typedef __attribute__((ext_vector_type(8))) unsigned short ushort8;

__device__ inline unsigned short f2bf_rn(float f) {
    union { float f; uint32_t u; } v; v.f = f;
    uint32_t u = v.u;
    uint32_t r = u + 0x7FFFu + ((u >> 16) & 1u);
    return (unsigned short)(r >> 16);
}

// pack two fp32 -> bf16 pair (round-half-up; absmax headroom 3x vs RNE, proven)
__device__ inline uint32_t pack_bf2(float a, float b) {
    union { float f; uint32_t u; } ua, ub;
    ua.f = a; ub.f = b;
    uint32_t x = ua.u + 0x8000u;
    uint32_t y = ub.u + 0x8000u;
    return (x >> 16) | (y & 0xFFFF0000u);
}

// Wc = bf16(W_shared + W_expert), 8 elems/thread
__global__ __launch_bounds__(256) void cvt_w_kernel(const float* __restrict__ ws,
                                                    const float* __restrict__ we,
                                                    unsigned short* __restrict__ wc) {
    const size_t i = ((size_t)blockIdx.x * 256 + threadIdx.x) * 8;
    const f32x4* p0 = (const f32x4*)(ws + i);
    const f32x4* p1 = (const f32x4*)(we + i);
    f32x4 a0 = p0[0], a1 = p0[1], b0 = p1[0], b1 = p1[1];
    ushort8 o;
    o[0] = f2bf_rn(a0[0] + b0[0]); o[1] = f2bf_rn(a0[1] + b0[1]);
    o[2] = f2bf_rn(a0[2] + b0[2]); o[3] = f2bf_rn(a0[3] + b0[3]);
    o[4] = f2bf_rn(a1[0] + b1[0]); o[5] = f2bf_rn(a1[1] + b1[1]);
    o[6] = f2bf_rn(a1[2] + b1[2]); o[7] = f2bf_rn(a1[3] + b1[3]);
    *(ushort8*)(wc + i) = o;
}

__device__ inline void gload16(const void* g, void* l) {
    __builtin_amdgcn_global_load_lds((const __attribute__((address_space(1))) void*)g,
                                     (__attribute__((address_space(3))) void*)l,
                                     16, 0, 0);
}

#define ASM_BARRIER()  asm volatile("s_barrier" ::: "memory")
#define WAIT_LGKM0()   asm volatile("s_waitcnt lgkmcnt(0)" ::: "memory")
#define WAIT_VM0()     asm volatile("s_waitcnt vmcnt(0)" ::: "memory")

// 8-phase (4 phases/K-tile, dbuf) 256x256x64 schedule, plain-HIP port of the
// m201 template. A (=X, fp32) reg-staged + converted + swizzled ds_write;
// B (=Wc, bf16) via global_load_lds with inverse-swizzled global source.
// LDS tiles [256][64] bf16 (128-B rows) with T2 XOR swizzle
//   lds_byte = row*128 + (colbyte ^ ((row&7)<<4))
// which makes the stride-128B ds_read_b128 fragment reads 2-way (free).
// Raw s_barrier + per-tile counted vmcnt: stages issued at ph1 are only
// drained at ph4 (~3 phases later) -> wait is ~free, loads span the tile.
__global__ __launch_bounds__(512, 2) void gemm8p(const float* __restrict__ X,
                                                 const unsigned short* __restrict__ Bt,
                                                 const float* __restrict__ bias,
                                                 float* __restrict__ C) {
    __shared__ unsigned char smem[131072];           // A: 2x32K @0, B: 2x32K @64K

    const int tid  = threadIdx.x;
    const int wave = tid >> 6;
    const int lane = tid & 63;

    // T1: XCD-contiguous swizzle. 256 blocks, 8 XCDs -> 32 blocks/XCD as
    // 8 bm-stripes x 4 bn (the 4 bn-blocks of a stripe share A via L2).
    const int bid = blockIdx.x;
    const int xcd = bid & 7;
    const int loc = bid >> 3;
    const int bm  = xcd * 8 + (loc >> 2);   // 0..63
    const int bn  = loc & 3;                // 0..3

    const int wm  = wave >> 2;              // 0..1 : rows wm*128..+128
    const int wnq = wave & 3;               // 0..3 : cols wnq*64..+64

    // fragment lane decomposition (16x16x32: row=lane&15, k-off=(lane>>4)*8)
    const int fr = lane & 15;
    const int fq = lane >> 4;
    const int sx  = (fr & 7) << 4;          // per-lane swizzle XOR (row&7 == fr&7)
    const int cb0 = (fq * 16) ^ sx;         // k-subtile 0 byte offset
    const int cb1 = cb0 ^ 64;               // k-subtile 1

    // ---- staging maps (all 8 waves stage both operands) ----
    // chunk g = i*512 + tid, i=0..3;  row = i*64 + (tid>>3), colchunk = tid&7
    const int srow   = tid >> 3;                       // + i*64
    const int scolc  = tid & 7;
    const int swrow  = (srow & 7) << 4;                // row&7 invariant in i
    // B: linear LDS dest (DMA), inverse-swizzled global source column
    const int bsrc_col = (scolc * 8) ^ ((srow & 7) << 3);   // elements
    const unsigned short* gBbase = Bt + (size_t)(bn * 256 + srow) * Kdim + bsrc_col;
    const int bdst = 65536 + wave * 1024 + lane * 16;       // + buf*32768 + i*8192
    // A: straight global source, swizzled ds_write dest
    const float* gAbase = X + (size_t)(bm * 256 + srow) * Kdim + scolc * 8;
    const int adst = srow * 128 + ((scolc * 16) ^ swrow);   // + buf*32768 + i*8192

    f32x4 acc[8][4] = {};

    // A-frag LDS byte offset (within buf): rows wm*128 + mq*64 + i*16 + fr
    const int abase = (wm * 128 + fr) * 128;
    // B-frag: rows wnq*64 + nq*32 + j*16 + fr
    const int bbase = 65536 + (wnq * 64 + fr) * 128;

    // ---- prologue: stage tile 0 into buf 0 ----
    {
        f32x4 av[8];
#pragma unroll
        for (int i = 0; i < 4; ++i) {
            const float* ga = gAbase + (size_t)i * 64 * Kdim;
            av[2 * i]     = *(const f32x4*)(ga);
            av[2 * i + 1] = *(const f32x4*)(ga + 4);
        }
#pragma unroll
        for (int i = 0; i < 4; ++i)
            gload16(gBbase + (size_t)i * 64 * Kdim, smem + bdst + i * 8192);
#pragma unroll
        for (int i = 0; i < 4; ++i) {
            uint4 w;
            w.x = pack_bf2(av[2 * i][0], av[2 * i][1]);
            w.y = pack_bf2(av[2 * i][2], av[2 * i][3]);
            w.z = pack_bf2(av[2 * i + 1][0], av[2 * i + 1][1]);
            w.w = pack_bf2(av[2 * i + 1][2], av[2 * i + 1][3]);
            *(uint4*)(smem + adst + i * 8192) = w;
        }
        WAIT_VM0();
        WAIT_LGKM0();
        ASM_BARRIER();
    }

    bf16x8 a[4][2], b0[2][2], b1[2][2];

    for (int kt = 0; kt < KTILES; ++kt) {
        const int bufo  = (kt & 1) * 32768;
        const int nbufo = bufo ^ 32768;
        const bool pf = (kt + 1 < KTILES);
        f32x4 av[8];

        // ---------- phase 1: stage-issue + a(mq0)+b(nq0) reads + MFMA q00 ----------
        if (pf) {
            const size_t ko = (size_t)(kt + 1) * 64;
#pragma unroll
            for (int i = 0; i < 4; ++i) {
                const float* ga = gAbase + (size_t)i * 64 * Kdim + ko;
                av[2 * i]     = *(const f32x4*)(ga);
                av[2 * i + 1] = *(const f32x4*)(ga + 4);
            }
#pragma unroll
            for (int i = 0; i < 4; ++i)
                gload16(gBbase + (size_t)i * 64 * Kdim + ko,
                        smem + (nbufo + bdst) + i * 8192);
        }
#pragma unroll
        for (int i = 0; i < 4; ++i) {
            a[i][0] = *(const bf16x8*)(smem + bufo + abase + i * 2048 + cb0);
            a[i][1] = *(const bf16x8*)(smem + bufo + abase + i * 2048 + cb1);
        }
#pragma unroll
        for (int j = 0; j < 2; ++j) {
            b0[j][0] = *(const bf16x8*)(smem + bufo + bbase + j * 2048 + cb0);
            b0[j][1] = *(const bf16x8*)(smem + bufo + bbase + j * 2048 + cb1);
        }
        ASM_BARRIER();
        WAIT_LGKM0();
        __builtin_amdgcn_s_setprio(1);
#pragma unroll
        for (int i = 0; i < 4; ++i)
#pragma unroll
            for (int j = 0; j < 2; ++j) {
                acc[i][j] = __builtin_amdgcn_mfma_f32_16x16x32_bf16(a[i][0], b0[j][0], acc[i][j], 0, 0, 0);
                acc[i][j] = __builtin_amdgcn_mfma_f32_16x16x32_bf16(a[i][1], b0[j][1], acc[i][j], 0, 0, 0);
            }
        __builtin_amdgcn_s_setprio(0);
        ASM_BARRIER();

        // ---------- phase 2: pack/write chunks 0-1 + b(nq1) reads + MFMA q01 ----------
        if (pf) {
#pragma unroll
            for (int i = 0; i < 2; ++i) {
                uint4 w;
                w.x = pack_bf2(av[2 * i][0], av[2 * i][1]);
                w.y = pack_bf2(av[2 * i][2], av[2 * i][3]);
                w.z = pack_bf2(av[2 * i + 1][0], av[2 * i + 1][1]);
                w.w = pack_bf2(av[2 * i + 1][2], av[2 * i + 1][3]);
                *(uint4*)(smem + (nbufo + adst) + i * 8192) = w;
            }
        }
#pragma unroll
        for (int j = 0; j < 2; ++j) {
            b1[j][0] = *(const bf16x8*)(smem + bufo + bbase + 4096 + j * 2048 + cb0);
            b1[j][1] = *(const bf16x8*)(smem + bufo + bbase + 4096 + j * 2048 + cb1);
        }
        ASM_BARRIER();
        WAIT_LGKM0();
        __builtin_amdgcn_s_setprio(1);
#pragma unroll
        for (int i = 0; i < 4; ++i)
#pragma unroll
            for (int j = 0; j < 2; ++j) {
                acc[i][2 + j] = __builtin_amdgcn_mfma_f32_16x16x32_bf16(a[i][0], b1[j][0], acc[i][2 + j], 0, 0, 0);
                acc[i][2 + j] = __builtin_amdgcn_mfma_f32_16x16x32_bf16(a[i][1], b1[j][1], acc[i][2 + j], 0, 0, 0);
            }
        __builtin_amdgcn_s_setprio(0);
        ASM_BARRIER();

        // ---------- phase 3: pack/write chunks 2-3 + a(mq1) reads + MFMA q10 ----------
        if (pf) {
#pragma unroll
            for (int i = 2; i < 4; ++i) {
                uint4 w;
                w.x = pack_bf2(av[2 * i][0], av[2 * i][1]);
                w.y = pack_bf2(av[2 * i][2], av[2 * i][3]);
                w.z = pack_bf2(av[2 * i + 1][0], av[2 * i + 1][1]);
                w.w = pack_bf2(av[2 * i + 1][2], av[2 * i + 1][3]);
                *(uint4*)(smem + (nbufo + adst) + i * 8192) = w;
            }
        }
#pragma unroll
        for (int i = 0; i < 4; ++i) {
            a[i][0] = *(const bf16x8*)(smem + bufo + abase + 8192 + i * 2048 + cb0);
            a[i][1] = *(const bf16x8*)(smem + bufo + abase + 8192 + i * 2048 + cb1);
        }
        ASM_BARRIER();
        WAIT_LGKM0();
        __builtin_amdgcn_s_setprio(1);
#pragma unroll
        for (int i = 0; i < 4; ++i)
#pragma unroll
            for (int j = 0; j < 2; ++j) {
                acc[4 + i][j] = __builtin_amdgcn_mfma_f32_16x16x32_bf16(a[i][0], b0[j][0], acc[4 + i][j], 0, 0, 0);
                acc[4 + i][j] = __builtin_amdgcn_mfma_f32_16x16x32_bf16(a[i][1], b0[j][1], acc[4 + i][j], 0, 0, 0);
            }
        __builtin_amdgcn_s_setprio(0);
        ASM_BARRIER();

        // ---------- phase 4: MFMA q11 + boundary drain ----------
        __builtin_amdgcn_s_setprio(1);
#pragma unroll
        for (int i = 0; i < 4; ++i)
#pragma unroll
            for (int j = 0; j < 2; ++j) {
                acc[4 + i][2 + j] = __builtin_amdgcn_mfma_f32_16x16x32_bf16(a[i][0], b1[j][0], acc[4 + i][2 + j], 0, 0, 0);
                acc[4 + i][2 + j] = __builtin_amdgcn_mfma_f32_16x16x32_bf16(a[i][1], b1[j][1], acc[4 + i][2 + j], 0, 0, 0);
            }
        __builtin_amdgcn_s_setprio(0);
        WAIT_VM0();      // own gload_lds (issued ph1, ~3 phases old) -> ~free
        WAIT_LGKM0();    // own ds_writes (ph2/ph3)
        ASM_BARRIER();   // all waves' stages for tile kt+1 now visible
    }

    // Epilogue: C/D layout col = lane&15, row = (lane>>4)*4 + reg  [m89-verified]
#pragma unroll
    for (int jj = 0; jj < 4; ++jj) {
        const int col = bn * 256 + wnq * 64 + jj * 16 + fr;
        const float bv = bias[col];
#pragma unroll
        for (int ii = 0; ii < 8; ++ii) {
            const int row = bm * 256 + wm * 128 + ii * 16 + fq * 4;
            float* p = C + (size_t)row * Ndim + col;
#pragma unroll
            for (int r = 0; r < 4; ++r)
                p[(size_t)r * Ndim] = acc[ii][jj][r] + bv;
        }
    }
}

extern "C" void kernel_launch(void* const* d_in, const int* in_sizes, int n_in,
                              void* d_out, int out_size, void* d_ws, size_t ws_size,
                              hipStream_t stream) {
    // inputs: x, cond, mask, W_shared, W_expert, W_gate, bias
    const float* x    = (const float*)d_in[0];
    const float* Wsh  = (const float*)d_in[3];
    const float* Wex  = (const float*)d_in[4];
    const float* bias = (const float*)d_in[6];
    float* out = (float*)d_out;

    unsigned short* Wbf = (unsigned short*)d_ws;  // 1024*1024 bf16 = 2 MiB

    hipLaunchKernelGGL(cvt_w_kernel, dim3((Ndim * Kdim) / (256 * 8)), dim3(256), 0, stream,
                       Wsh, Wex, Wbf);
    hipLaunchKernelGGL(gemm8p, dim3((Mdim / 256) * (Ndim / 256)), dim3(512), 0, stream,
                       x, Wbf, bias, out);
}

// Round 5
// 184.828 us; speedup vs baseline: 1.0494x; 1.0494x over previous
//
#include <hip/hip_runtime.h>
#include <hip/hip_bf16.h>
#include <stdint.h>

// out = x @ (W_shared + W_expert)^T + bias   (MoE collapses: positional routing,
// shared expert weights, normalized top-2 gate weights sum to 1)
static constexpr int Mdim = 16384;  // T = B*N tokens
static constexpr int Ndim = 1024;
static constexpr int Kdim = 1024;
// 8-phase 256^2 template: BM=BN=256, BK=64, 512 thr / 8 waves (2M x 4N)
static constexpr int KTILES = Kdim / 64;  // 16

typedef __attribute__((ext_vector_type(8))) __bf16 bf16x8;
typedef __attribute__((ext_vector_type(4))) float f32x4;
typedef __attribute__((ext_vector_type(8))) unsigned short ushort8;

__device__ inline unsigned short f2bf_rn(float f) {
    union { float f; uint32_t u; } v; v.f = f;
    uint32_t u = v.u;
    uint32_t r = u + 0x7FFFu + ((u >> 16) & 1u);
    return (unsigned short)(r >> 16);
}

// pack two fp32 -> bf16 pair (round-half-up; absmax headroom 3x vs RNE, proven)
__device__ inline uint32_t pack_bf2(float a, float b) {
    union { float f; uint32_t u; } ua, ub;
    ua.f = a; ub.f = b;
    uint32_t x = ua.u + 0x8000u;
    uint32_t y = ub.u + 0x8000u;
    return (x >> 16) | (y & 0xFFFF0000u);
}

// Wc = bf16(W_shared + W_expert), 8 elems/thread
__global__ __launch_bounds__(256) void cvt_w_kernel(const float* __restrict__ ws,
                                                    const float* __restrict__ we,
                                                    unsigned short* __restrict__ wc) {
    const size_t i = ((size_t)blockIdx.x * 256 + threadIdx.x) * 8;
    const f32x4* p0 = (const f32x4*)(ws + i);
    const f32x4* p1 = (const f32x4*)(we + i);
    f32x4 a0 = p0[0], a1 = p0[1], b0 = p1[0], b1 = p1[1];
    ushort8 o;
    o[0] = f2bf_rn(a0[0] + b0[0]); o[1] = f2bf_rn(a0[1] + b0[1]);
    o[2] = f2bf_rn(a0[2] + b0[2]); o[3] = f2bf_rn(a0[3] + b0[3]);
    o[4] = f2bf_rn(a1[0] + b1[0]); o[5] = f2bf_rn(a1[1] + b1[1]);
    o[6] = f2bf_rn(a1[2] + b1[2]); o[7] = f2bf_rn(a1[3] + b1[3]);
    *(ushort8*)(wc + i) = o;
}

__device__ inline void gload16(const void* g, void* l) {
    __builtin_amdgcn_global_load_lds((const __attribute__((address_space(1))) void*)g,
                                     (__attribute__((address_space(3))) void*)l,
                                     16, 0, 0);
}

#define ASM_BARRIER()  asm volatile("s_barrier" ::: "memory")
#define WAIT_LGKM0()   asm volatile("s_waitcnt lgkmcnt(0)" ::: "memory")
#define WAIT_VM8()     asm volatile("s_waitcnt vmcnt(8)" ::: "memory")
#define WAIT_VM0()     asm volatile("s_waitcnt vmcnt(0)" ::: "memory")

// 8-phase (4 phases/K-tile, dbuf) 256x256x64, never-drain counted vmcnt.
// Pipeline per tile kt:
//   ph1: ds_read a(mq0)+b(nq0) | issue 4x gload_lds B(kt+1)->buf^1 | MFMA q00
//   ph2: pack av(=A(kt+1)) ch0-1 -> buf^1 | ds_read b(nq1) | MFMA q01
//        (compiler's pack-wait = vmcnt(4): retires A flats, leaves B flying)
//   ph3: pack ch2-3 | ds_read a(mq1) | MFMA q10
//   ph4: issue 8x flat A(kt+2)->av | MFMA q11 | s_waitcnt vmcnt(8)  <-- counted:
//        retires exactly the 4 B gloads (oldest, in-order), A stays in flight
//        | lgkmcnt(0) | s_barrier
// A (=X, fp32) reg-staged + pack_bf2 + swizzled ds_write; B (=Wc, bf16) via
// global_load_lds with inverse-swizzled global source. T2 swizzle:
//   lds_byte = row*128 + (colbyte ^ ((row&7)<<4))  -> 0 bank conflicts (R2 PMC).
__global__ __launch_bounds__(512, 2) void gemm8p(const float* __restrict__ X,
                                                 const unsigned short* __restrict__ Bt,
                                                 const float* __restrict__ bias,
                                                 float* __restrict__ C) {
    __shared__ unsigned char smem[131072];           // A: 2x32K @0, B: 2x32K @64K

    const int tid  = threadIdx.x;
    const int wave = tid >> 6;
    const int lane = tid & 63;

    // T1: XCD-contiguous swizzle. 256 blocks, 8 XCDs -> 32 blocks/XCD as
    // 8 bm-stripes x 4 bn (the 4 bn-blocks of a stripe share A via L2).
    const int bid = blockIdx.x;
    const int xcd = bid & 7;
    const int loc = bid >> 3;
    const int bm  = xcd * 8 + (loc >> 2);   // 0..63
    const int bn  = loc & 3;                // 0..3

    const int wm  = wave >> 2;              // 0..1 : rows wm*128..+128
    const int wnq = wave & 3;               // 0..3 : cols wnq*64..+64

    // fragment lane decomposition (16x16x32: row=lane&15, k-off=(lane>>4)*8)
    const int fr = lane & 15;
    const int fq = lane >> 4;
    const int sx  = (fr & 7) << 4;          // per-lane swizzle XOR (row&7 == fr&7)
    const int cb0 = (fq * 16) ^ sx;         // k-subtile 0 byte offset
    const int cb1 = cb0 ^ 64;               // k-subtile 1

    // ---- staging maps (all 8 waves stage both operands) ----
    // chunk g = i*512 + tid, i=0..3;  row = i*64 + (tid>>3), colchunk = tid&7
    const int srow   = tid >> 3;                       // + i*64
    const int scolc  = tid & 7;
    const int swrow  = (srow & 7) << 4;                // row&7 invariant in i
    // B: linear LDS dest (DMA), inverse-swizzled global source column
    const int bsrc_col = (scolc * 8) ^ ((srow & 7) << 3);   // elements
    const unsigned short* gBbase = Bt + (size_t)(bn * 256 + srow) * Kdim + bsrc_col;
    const int bdst = 65536 + wave * 1024 + lane * 16;       // + buf*32768 + i*8192
    // A: straight global source, swizzled ds_write dest
    const float* gAbase = X + (size_t)(bm * 256 + srow) * Kdim + scolc * 8;
    const int adst = srow * 128 + ((scolc * 16) ^ swrow);   // + buf*32768 + i*8192

    f32x4 acc[8][4] = {};
    f32x4 av[8];   // A(kt+1) staging registers, live across the loop back-edge

    // A-frag LDS byte offset (within buf): rows wm*128 + mq*64 + i*16 + fr
    const int abase = (wm * 128 + fr) * 128;
    // B-frag: rows wnq*64 + nq*32 + j*16 + fr
    const int bbase = 65536 + (wnq * 64 + fr) * 128;

    // ---- prologue: stage tile 0 into buf 0, issue A(1) flats before the wait ----
    {
        f32x4 a0v[8];
#pragma unroll
        for (int i = 0; i < 4; ++i) {
            const float* ga = gAbase + (size_t)i * 64 * Kdim;
            a0v[2 * i]     = *(const f32x4*)(ga);
            a0v[2 * i + 1] = *(const f32x4*)(ga + 4);
        }
#pragma unroll
        for (int i = 0; i < 4; ++i)
            gload16(gBbase + (size_t)i * 64 * Kdim, smem + bdst + i * 8192);
#pragma unroll
        for (int i = 0; i < 4; ++i) {   // compiler waits A(0) here, B(0) stays out
            uint4 w;
            w.x = pack_bf2(a0v[2 * i][0], a0v[2 * i][1]);
            w.y = pack_bf2(a0v[2 * i][2], a0v[2 * i][3]);
            w.z = pack_bf2(a0v[2 * i + 1][0], a0v[2 * i + 1][1]);
            w.w = pack_bf2(a0v[2 * i + 1][2], a0v[2 * i + 1][3]);
            *(uint4*)(smem + adst + i * 8192) = w;
        }
        // issue A(1) so the B(0) wait below is counted, not a drain
#pragma unroll
        for (int i = 0; i < 4; ++i) {
            const float* ga = gAbase + (size_t)i * 64 * Kdim + 64;
            av[2 * i]     = *(const f32x4*)(ga);
            av[2 * i + 1] = *(const f32x4*)(ga + 4);
        }
        WAIT_VM8();      // retire the 4 B(0) gloads; A(1) stays in flight
        WAIT_LGKM0();
        ASM_BARRIER();
    }

    bf16x8 a[4][2], b0[2][2], b1[2][2];

    for (int kt = 0; kt < KTILES; ++kt) {
        const int bufo  = (kt & 1) * 32768;
        const int nbufo = bufo ^ 32768;
        const bool pf  = (kt + 1 < KTILES);   // stage tile kt+1 (pack + B gload)
        const bool pf2 = (kt + 2 < KTILES);   // issue A(kt+2) flats at ph4

        // ---------- phase 1: B(kt+1) gload issue + a(mq0)+b(nq0) reads + MFMA q00 ----------
        if (pf) {
            const size_t ko = (size_t)(kt + 1) * 64;
#pragma unroll
            for (int i = 0; i < 4; ++i)
                gload16(gBbase + (size_t)i * 64 * Kdim + ko,
                        smem + (nbufo + bdst) + i * 8192);
        }
#pragma unroll
        for (int i = 0; i < 4; ++i) {
            a[i][0] = *(const bf16x8*)(smem + bufo + abase + i * 2048 + cb0);
            a[i][1] = *(const bf16x8*)(smem + bufo + abase + i * 2048 + cb1);
        }
#pragma unroll
        for (int j = 0; j < 2; ++j) {
            b0[j][0] = *(const bf16x8*)(smem + bufo + bbase + j * 2048 + cb0);
            b0[j][1] = *(const bf16x8*)(smem + bufo + bbase + j * 2048 + cb1);
        }
        ASM_BARRIER();
        WAIT_LGKM0();
        __builtin_amdgcn_s_setprio(1);
#pragma unroll
        for (int i = 0; i < 4; ++i)
#pragma unroll
            for (int j = 0; j < 2; ++j) {
                acc[i][j] = __builtin_amdgcn_mfma_f32_16x16x32_bf16(a[i][0], b0[j][0], acc[i][j], 0, 0, 0);
                acc[i][j] = __builtin_amdgcn_mfma_f32_16x16x32_bf16(a[i][1], b0[j][1], acc[i][j], 0, 0, 0);
            }
        __builtin_amdgcn_s_setprio(0);
        ASM_BARRIER();

        // ---------- phase 2: pack A(kt+1) ch0-1 + b(nq1) reads + MFMA q01 ----------
        if (pf) {
#pragma unroll
            for (int i = 0; i < 2; ++i) {   // compiler emits vmcnt(4): A done, B flying
                uint4 w;
                w.x = pack_bf2(av[2 * i][0], av[2 * i][1]);
                w.y = pack_bf2(av[2 * i][2], av[2 * i][3]);
                w.z = pack_bf2(av[2 * i + 1][0], av[2 * i + 1][1]);
                w.w = pack_bf2(av[2 * i + 1][2], av[2 * i + 1][3]);
                *(uint4*)(smem + (nbufo + adst) + i * 8192) = w;
            }
        }
#pragma unroll
        for (int j = 0; j < 2; ++j) {
            b1[j][0] = *(const bf16x8*)(smem + bufo + bbase + 4096 + j * 2048 + cb0);
            b1[j][1] = *(const bf16x8*)(smem + bufo + bbase + 4096 + j * 2048 + cb1);
        }
        ASM_BARRIER();
        WAIT_LGKM0();
        __builtin_amdgcn_s_setprio(1);
#pragma unroll
        for (int i = 0; i < 4; ++i)
#pragma unroll
            for (int j = 0; j < 2; ++j) {
                acc[i][2 + j] = __builtin_amdgcn_mfma_f32_16x16x32_bf16(a[i][0], b1[j][0], acc[i][2 + j], 0, 0, 0);
                acc[i][2 + j] = __builtin_amdgcn_mfma_f32_16x16x32_bf16(a[i][1], b1[j][1], acc[i][2 + j], 0, 0, 0);
            }
        __builtin_amdgcn_s_setprio(0);
        ASM_BARRIER();

        // ---------- phase 3: pack ch2-3 + a(mq1) reads + MFMA q10 ----------
        if (pf) {
#pragma unroll
            for (int i = 2; i < 4; ++i) {
                uint4 w;
                w.x = pack_bf2(av[2 * i][0], av[2 * i][1]);
                w.y = pack_bf2(av[2 * i][2], av[2 * i][3]);
                w.z = pack_bf2(av[2 * i + 1][0], av[2 * i + 1][1]);
                w.w = pack_bf2(av[2 * i + 1][2], av[2 * i + 1][3]);
                *(uint4*)(smem + (nbufo + adst) + i * 8192) = w;
            }
        }
#pragma unroll
        for (int i = 0; i < 4; ++i) {
            a[i][0] = *(const bf16x8*)(smem + bufo + abase + 8192 + i * 2048 + cb0);
            a[i][1] = *(const bf16x8*)(smem + bufo + abase + 8192 + i * 2048 + cb1);
        }
        ASM_BARRIER();
        WAIT_LGKM0();
        __builtin_amdgcn_s_setprio(1);
#pragma unroll
        for (int i = 0; i < 4; ++i)
#pragma unroll
            for (int j = 0; j < 2; ++j) {
                acc[4 + i][j] = __builtin_amdgcn_mfma_f32_16x16x32_bf16(a[i][0], b0[j][0], acc[4 + i][j], 0, 0, 0);
                acc[4 + i][j] = __builtin_amdgcn_mfma_f32_16x16x32_bf16(a[i][1], b0[j][1], acc[4 + i][j], 0, 0, 0);
            }
        __builtin_amdgcn_s_setprio(0);
        ASM_BARRIER();

        // ---------- phase 4: issue A(kt+2) + MFMA q11 + COUNTED boundary wait ----------
        if (pf2) {
            const size_t ko = (size_t)(kt + 2) * 64;
#pragma unroll
            for (int i = 0; i < 4; ++i) {
                const float* ga = gAbase + (size_t)i * 64 * Kdim + ko;
                av[2 * i]     = *(const f32x4*)(ga);
                av[2 * i + 1] = *(const f32x4*)(ga + 4);
            }
        }
        __builtin_amdgcn_s_setprio(1);
#pragma unroll
        for (int i = 0; i < 4; ++i)
#pragma unroll
            for (int j = 0; j < 2; ++j) {
                acc[4 + i][2 + j] = __builtin_amdgcn_mfma_f32_16x16x32_bf16(a[i][0], b1[j][0], acc[4 + i][2 + j], 0, 0, 0);
                acc[4 + i][2 + j] = __builtin_amdgcn_mfma_f32_16x16x32_bf16(a[i][1], b1[j][1], acc[4 + i][2 + j], 0, 0, 0);
            }
        __builtin_amdgcn_s_setprio(0);
        if (pf2) {
            WAIT_VM8();   // retire exactly the 4 B(kt+1) gloads; A(kt+2) stays out
        } else {
            WAIT_VM0();   // tail (kt=14: drain B(15); kt=15: empty)
        }
        WAIT_LGKM0();     // own ds_writes (ph2/ph3)
        ASM_BARRIER();    // all waves' stages for tile kt+1 now visible
    }

    // Epilogue: C/D layout col = lane&15, row = (lane>>4)*4 + reg  [m89-verified]
#pragma unroll
    for (int jj = 0; jj < 4; ++jj) {
        const int col = bn * 256 + wnq * 64 + jj * 16 + fr;
        const float bv = bias[col];
#pragma unroll
        for (int ii = 0; ii < 8; ++ii) {
            const int row = bm * 256 + wm * 128 + ii * 16 + fq * 4;
            float* p = C + (size_t)row * Ndim + col;
#pragma unroll
            for (int r = 0; r < 4; ++r)
                p[(size_t)r * Ndim] = acc[ii][jj][r] + bv;
        }
    }
}

extern "C" void kernel_launch(void* const* d_in, const int* in_sizes, int n_in,
                              void* d_out, int out_size, void* d_ws, size_t ws_size,
                              hipStream_t stream) {
    // inputs: x, cond, mask, W_shared, W_expert, W_gate, bias
    const float* x    = (const float*)d_in[0];
    const float* Wsh  = (const float*)d_in[3];
    const float* Wex  = (const float*)d_in[4];
    const float* bias = (const float*)d_in[6];
    float* out = (float*)d_out;

    unsigned short* Wbf = (unsigned short*)d_ws;  // 1024*1024 bf16 = 2 MiB

    hipLaunchKernelGGL(cvt_w_kernel, dim3((Ndim * Kdim) / (256 * 8)), dim3(256), 0, stream,
                       Wsh, Wex, Wbf);
    hipLaunchKernelGGL(gemm8p, dim3((Mdim / 256) * (Ndim / 256)), dim3(512), 0, stream,
                       x, Wbf, bias, out);
}